// Round 11
// baseline (742.578 us; speedup 1.0000x reference)
//
#include <hip/hip_runtime.h>

#define R 5
#define U 100000
#define M 50000
#define E 2000000
#define F 10
#define D 50

#define TE (R * E)                      // 10,000,000 edges per direction
#define NBLK 192                        // phase A/C block count (sized so ws fits 86MB)
#define CHUNK ((TE + NBLK - 1) / NBLK)  // 52,084 edges per block
#define BSZ 256

// balanced buckets: user avg degree 20, item avg degree 40 -> equal edges/bucket
#define NKEY_U 128                      // user keys per bucket (7 bits)
#define NKEY_I 64                       // item keys per bucket (6 bits)
#define KS_U (R * U)                    // 500,000 user keys
#define KS_I (R * M)                    // 250,000 item keys
#define NBU_U ((KS_U + NKEY_U - 1) / NKEY_U)  // 3907
#define NBU_I ((KS_I + NKEY_I - 1) / NKEY_I)  // 3907
#define NBU_T (NBU_U + NBU_I)                 // 7814
#define OFFI (NBU_U * NBLK)                   // item region start in S
#define GTOT (OFFI + NBU_I * NBLK)            // 1,500,288
#define NS1 ((GTOT + 1023) / 1024)            // 1466 scan blocks
#define S2K ((NS1 + 255) / 256)               // 6 entries/thread in scan2

#define CAP 3328                        // max edges/bucket (mean 2560 + 15 sigma)
#define ASTR 11                         // acc stride (gcd(11,32)=1 -> all banks)

// ======================= bucketed counting-sort path =======================

__global__ __launch_bounds__(BSZ) void phaseA(const int* __restrict__ esrc,
                                              const int* __restrict__ edst,
                                              unsigned* __restrict__ ghist) {
    __shared__ unsigned hist[NBU_T];
    for (int i = threadIdx.x; i < NBU_T; i += BSZ) hist[i] = 0;
    __syncthreads();
    int b = blockIdx.x;
    int lo = b * CHUNK, hi = min(lo + CHUNK, TE);
    for (int i = lo + threadIdx.x; i < hi; i += BSZ) {
        unsigned r = (unsigned)i / (unsigned)E;
        int s = esrc[i], d = edst[i];
        unsigned ku = r * U + (unsigned)s;
        unsigned ki = r * M + (unsigned)d;
        atomicAdd(&hist[ku >> 7], 1u);
        atomicAdd(&hist[NBU_U + (ki >> 6)], 1u);
    }
    __syncthreads();
    for (int j = threadIdx.x; j < NBU_T; j += BSZ) {
        unsigned idx = (j < NBU_U) ? (unsigned)j * NBLK + b
                                   : OFFI + (unsigned)(j - NBU_U) * NBLK + b;
        ghist[idx] = hist[j];
    }
}

// Exclusive scan over ghist IN PLACE (S == ghist), 3 kernels.
__global__ __launch_bounds__(BSZ) void scan1(unsigned* __restrict__ S,
                                             unsigned* __restrict__ psum) {
    __shared__ unsigned sh[BSZ];
    int base = blockIdx.x * 1024 + threadIdx.x * 4;
    unsigned v[4], tsum = 0;
    for (int k = 0; k < 4; k++) {
        int i = base + k;
        v[k] = (i < GTOT) ? S[i] : 0u;
        tsum += v[k];
    }
    sh[threadIdx.x] = tsum;
    __syncthreads();
    for (int off = 1; off < BSZ; off <<= 1) {
        unsigned t = (threadIdx.x >= off) ? sh[threadIdx.x - off] : 0u;
        __syncthreads();
        sh[threadIdx.x] += t;
        __syncthreads();
    }
    unsigned ex = sh[threadIdx.x] - tsum;
    for (int k = 0; k < 4; k++) {
        int i = base + k;
        if (i < GTOT) S[i] = ex;
        ex += v[k];
    }
    if (threadIdx.x == BSZ - 1) psum[blockIdx.x] = sh[BSZ - 1];
}

__global__ __launch_bounds__(BSZ) void scan2(unsigned* __restrict__ psum) {
    __shared__ unsigned sh[BSZ];
    unsigned v[S2K], tsum = 0;
    int base = threadIdx.x * S2K;
    for (int k = 0; k < S2K; k++) {
        int i = base + k;
        v[k] = (i < NS1) ? psum[i] : 0u;
        tsum += v[k];
    }
    sh[threadIdx.x] = tsum;
    __syncthreads();
    for (int off = 1; off < BSZ; off <<= 1) {
        unsigned t = (threadIdx.x >= off) ? sh[threadIdx.x - off] : 0u;
        __syncthreads();
        sh[threadIdx.x] += t;
        __syncthreads();
    }
    unsigned ex = sh[threadIdx.x] - tsum;
    for (int k = 0; k < S2K; k++) {
        int i = base + k;
        if (i < NS1) psum[i] = ex;
        ex += v[k];
    }
}

__global__ __launch_bounds__(BSZ) void scan3(unsigned* __restrict__ S,
                                             const unsigned* __restrict__ psum) {
    unsigned add = psum[blockIdx.x];
    int base = blockIdx.x * 1024 + threadIdx.x * 4;
    for (int k = 0; k < 4; k++) {
        int i = base + k;
        if (i < GTOT) S[i] += add;
    }
}

// Scatter edges into bucket-grouped payload array. LDS cursor atomics only.
// user payload = local(7b) | item_id<<7 ; item payload = local(6b) | user_id<<6
__global__ __launch_bounds__(BSZ) void phaseC(const int* __restrict__ esrc,
                                              const int* __restrict__ edst,
                                              const unsigned* __restrict__ S,
                                              unsigned* __restrict__ sorted) {
    __shared__ unsigned cur[NBU_T];
    int b = blockIdx.x;
    for (int j = threadIdx.x; j < NBU_T; j += BSZ) {
        unsigned idx = (j < NBU_U) ? (unsigned)j * NBLK + b
                                   : OFFI + (unsigned)(j - NBU_U) * NBLK + b;
        cur[j] = S[idx];
    }
    __syncthreads();
    int lo = b * CHUNK, hi = min(lo + CHUNK, TE);
    for (int i = lo + threadIdx.x; i < hi; i += BSZ) {
        unsigned r = (unsigned)i / (unsigned)E;
        int s = esrc[i], d = edst[i];
        unsigned ku = r * U + (unsigned)s;
        unsigned ki = r * M + (unsigned)d;
        unsigned pu = atomicAdd(&cur[ku >> 7], 1u);
        sorted[pu] = (ku & 127u) | ((unsigned)d << 7);
        unsigned pi = atomicAdd(&cur[NBU_U + (ki >> 6)], 1u);
        sorted[pi] = (ki & 63u) | ((unsigned)s << 6);
    }
}

// phaseD v5: in-LDS counting sort + register segmented reduce, tuned for
// occupancy: ~20KB LDS -> 8 blocks/CU (32 waves, 2x round-8's 4 blocks),
// balanced ~2560-edge buckets in both directions.
__global__ __launch_bounds__(BSZ, 8) void phaseD(
    const unsigned* __restrict__ sorted, const unsigned* __restrict__ S,
    const float* __restrict__ fsrc_u, const float* __restrict__ fdst_u,
    const float* __restrict__ wsf_u, const float* __restrict__ wnf_u,
    const float* __restrict__ bia_u,
    const float* __restrict__ fsrc_i, const float* __restrict__ fdst_i,
    const float* __restrict__ wsf_i, const float* __restrict__ wnf_i,
    const float* __restrict__ bia_i,
    float* __restrict__ out_u, float* __restrict__ out_i) {
    __shared__ unsigned sbuf[CAP];          // key-sorted payloads (13.3KB)
    __shared__ float acc[NKEY_U * ASTR];    // per-key sums (5.6KB, stride 11)
    __shared__ unsigned hist[NKEY_U];       // per-key degree
    __shared__ unsigned cur[NKEY_U];        // scan + scatter cursors
    __shared__ unsigned rbase[NKEY_U];      // r(key) * NSRC

    // per-direction bijective XCD swizzle (NBU_U == NBU_I == 3907)
    unsigned orig = blockIdx.x;
    unsigned bkt;
    {
        unsigned o = (orig < NBU_U) ? orig : orig - NBU_U;
        const unsigned q = NBU_U / 8u, rem = NBU_U % 8u;
        unsigned x = o & 7u, off = o >> 3;
        unsigned m = (x < rem ? x * (q + 1u) : rem * (q + 1u) + (x - rem) * q) + off;
        bkt = (orig < NBU_U) ? m : NBU_U + m;
    }

    bool isU = bkt < NBU_U;
    int j = isU ? (int)bkt : (int)bkt - NBU_U;
    unsigned N = isU ? U : M;
    unsigned NSRC = isU ? M : U;
    unsigned NKEY = isU ? NKEY_U : NKEY_I;
    unsigned KM = NKEY - 1u;                 // key mask
    unsigned KSH = isU ? 7u : 6u;            // src shift
    const float* fsrc = isU ? fsrc_u : fsrc_i;

    unsigned sbase = isU ? 0u : (unsigned)OFFI;
    unsigned lo = S[sbase + (unsigned)j * NBLK];
    unsigned hi = (!isU && j + 1 == NBU_I) ? (unsigned)(2 * TE)
                                           : S[sbase + (unsigned)(j + 1) * NBLK];
    unsigned len = hi - lo;
    unsigned keybase = (unsigned)j * NKEY;
    int tid = threadIdx.x;

    for (int t = tid; t < NKEY_U * ASTR; t += BSZ) acc[t] = 0.f;
    if (tid < NKEY_U) {
        hist[tid] = 0u;
        unsigned key = keybase + (unsigned)tid;
        unsigned r = (key < (unsigned)R * N) ? key / N : 0u;
        rbase[tid] = r * NSRC;
    }
    __syncthreads();

    if (len <= CAP) {
        // ---- step 1: per-key histogram (1 LDS atomic / edge) ----
        for (unsigned e = lo + tid; e < hi; e += BSZ)
            atomicAdd(&hist[sorted[e] & KM], 1u);
        __syncthreads();
        // ---- step 2: exclusive scan of hist -> cur (uniform barriers) ----
        if (tid < NKEY_U) cur[tid] = hist[tid];
        __syncthreads();
        for (int off = 1; off < NKEY_U; off <<= 1) {
            unsigned t = 0;
            if (tid < NKEY_U && tid >= off) t = cur[tid - off];
            __syncthreads();
            if (tid < NKEY_U && tid >= off) cur[tid] += t;
            __syncthreads();
        }
        if (tid < NKEY_U) cur[tid] -= hist[tid];
        __syncthreads();
        // ---- step 3: scatter into key-sorted LDS array ----
        for (unsigned e = lo + tid; e < hi; e += BSZ) {
            unsigned pay = sorted[e];
            unsigned pos = atomicAdd(&cur[pay & KM], 1u);
            sbuf[pos] = pay;
        }
        __syncthreads();
        // ---- step 4: register segmented reduce over equal slices ----
        unsigned L = (len + BSZ - 1) / BSZ;
        unsigned i0 = (unsigned)tid * L;
        unsigned i1 = min(i0 + L, len);
        if (i0 < i1) {
            int curKey = -1;
            float A0 = 0, A1 = 0, A2 = 0, A3 = 0, A4 = 0,
                  A5 = 0, A6 = 0, A7 = 0, A8 = 0, A9 = 0;
#define FLUSH_ACC()                                                        \
    do {                                                                   \
        if (curKey >= 0) {                                                 \
            float* ap = acc + curKey * ASTR;                               \
            atomicAdd(ap + 0, A0); atomicAdd(ap + 1, A1);                  \
            atomicAdd(ap + 2, A2); atomicAdd(ap + 3, A3);                  \
            atomicAdd(ap + 4, A4); atomicAdd(ap + 5, A5);                  \
            atomicAdd(ap + 6, A6); atomicAdd(ap + 7, A7);                  \
            atomicAdd(ap + 8, A8); atomicAdd(ap + 9, A9);                  \
        }                                                                  \
    } while (0)
#define ZERO_ACC() A0=A1=A2=A3=A4=A5=A6=A7=A8=A9=0.f
            unsigned i = i0;
            for (; i + 1 < i1; i += 2) {
                unsigned p0 = sbuf[i], p1 = sbuf[i + 1];
                unsigned k0 = p0 & KM, s0 = p0 >> KSH;
                unsigned k1 = p1 & KM, s1 = p1 >> KSH;
                const float2* r0 = (const float2*)(fsrc + (size_t)(rbase[k0] + s0) * F);
                const float2* r1 = (const float2*)(fsrc + (size_t)(rbase[k1] + s1) * F);
                float2 x0 = r0[0], x1 = r0[1], x2 = r0[2], x3 = r0[3], x4 = r0[4];
                float2 y0 = r1[0], y1 = r1[1], y2 = r1[2], y3 = r1[3], y4 = r1[4];
                if ((int)k0 != curKey) { FLUSH_ACC(); curKey = (int)k0; ZERO_ACC(); }
                A0 += x0.x; A1 += x0.y; A2 += x1.x; A3 += x1.y; A4 += x2.x;
                A5 += x2.y; A6 += x3.x; A7 += x3.y; A8 += x4.x; A9 += x4.y;
                if ((int)k1 != curKey) { FLUSH_ACC(); curKey = (int)k1; ZERO_ACC(); }
                A0 += y0.x; A1 += y0.y; A2 += y1.x; A3 += y1.y; A4 += y2.x;
                A5 += y2.y; A6 += y3.x; A7 += y3.y; A8 += y4.x; A9 += y4.y;
            }
            if (i < i1) {
                unsigned p0 = sbuf[i];
                unsigned k0 = p0 & KM, s0 = p0 >> KSH;
                const float2* r0 = (const float2*)(fsrc + (size_t)(rbase[k0] + s0) * F);
                float2 x0 = r0[0], x1 = r0[1], x2 = r0[2], x3 = r0[3], x4 = r0[4];
                if ((int)k0 != curKey) { FLUSH_ACC(); curKey = (int)k0; ZERO_ACC(); }
                A0 += x0.x; A1 += x0.y; A2 += x1.x; A3 += x1.y; A4 += x2.x;
                A5 += x2.y; A6 += x3.x; A7 += x3.y; A8 += x4.x; A9 += x4.y;
            }
            FLUSH_ACC();
#undef FLUSH_ACC
#undef ZERO_ACC
        }
    } else {
        // overflow fallback (statistically unreachable): per-edge atomics
        for (unsigned e = lo + tid; e < hi; e += BSZ) {
            unsigned pay = sorted[e];
            unsigned l = pay & KM, s = pay >> KSH;
            const float2* row = (const float2*)(fsrc + (size_t)(rbase[l] + s) * F);
            float* a = acc + l * ASTR;
#pragma unroll
            for (int k = 0; k < 5; k++) {
                float2 v = row[k];
                atomicAdd(a + 2 * k, v.x);
                atomicAdd(a + 2 * k + 1, v.y);
            }
            atomicAdd(&hist[l], 1u);
        }
    }
    __syncthreads();

    // ---- epilogue: fused projection ----
    const float* fdst = isU ? fdst_u : fdst_i;
    const float* wsf = isU ? wsf_u : wsf_i;
    const float* wnf = isU ? wnf_u : wnf_i;
    const float* bia = isU ? bia_u : bia_i;
    float* out = isU ? out_u : out_i;

    int tot = (int)NKEY * D;
    for (int o = tid; o < tot; o += BSZ) {
        int local = o / D, d = o - local * D;
        unsigned key = keybase + (unsigned)local;
        if (key >= (unsigned)(R)*N) continue;
        unsigned r = key / N, n = key - r * N;
        float inv = 1.f / fmaxf((float)hist[local], 1.f);
        const float* fd = fdst + ((size_t)r * N + n) * F;
        const float* a = acc + local * ASTR;
        const float* wsp = wsf + (size_t)r * F * D + d;
        const float* wnp = wnf + (size_t)r * F * D + d;
        float o1 = bia[r * D + d], o2 = 0.f;
#pragma unroll
        for (int f = 0; f < F; f++) {
            o1 += fd[f] * wsp[(size_t)f * D];
            o2 += a[f] * wnp[(size_t)f * D];
        }
        out[(size_t)n * (R * D) + r * D + d] = o1 + o2 * inv;
    }
}

// ======================= round-1 fallback (small ws) =======================
#define SUM_I_OFF 0
#define CNT_I_OFF ((size_t)R * M * F)
#define SUM_U_OFF (CNT_I_OFF + (size_t)R * M)
#define CNT_U_OFF (SUM_U_OFF + (size_t)R * U * F)
#define WS_FLOATS (CNT_U_OFF + (size_t)R * U)

__global__ void scatter_edges(const int* __restrict__ esrc, const int* __restrict__ edst,
                              const float* __restrict__ feat_u_fwd,
                              const float* __restrict__ feat_i_rev, float* __restrict__ ws) {
    float* sum_i = ws + SUM_I_OFF;
    float* cnt_i = ws + CNT_I_OFF;
    float* sum_u = ws + SUM_U_OFF;
    float* cnt_u = ws + CNT_U_OFF;
    const int total = R * E;
    for (int idx = blockIdx.x * blockDim.x + threadIdx.x; idx < total;
         idx += gridDim.x * blockDim.x) {
        int r = idx / E;
        int s = esrc[idx], d = edst[idx];
        const float* fu = feat_u_fwd + ((size_t)r * U + s) * F;
        const float* fi = feat_i_rev + ((size_t)r * M + d) * F;
        float* si = sum_i + ((size_t)r * M + d) * F;
        float* su = sum_u + ((size_t)r * U + s) * F;
#pragma unroll
        for (int f = 0; f < F; ++f) {
            atomicAdd(si + f, fu[f]);
            atomicAdd(su + f, fi[f]);
        }
        atomicAdd(cnt_i + (size_t)r * M + d, 1.0f);
        atomicAdd(cnt_u + (size_t)r * U + s, 1.0f);
    }
}

__global__ void finalize_nodes(int N, const float* __restrict__ feat_dst,
                               const float* __restrict__ w_self, const float* __restrict__ w_neigh,
                               const float* __restrict__ bias, const float* __restrict__ sum,
                               const float* __restrict__ cnt, float* __restrict__ out) {
    int idx = blockIdx.x * blockDim.x + threadIdx.x;
    int total = N * R * D;
    if (idx >= total) return;
    int n = idx / (R * D);
    int rd = idx - n * (R * D);
    int r = rd / D;
    int d = rd - r * D;
    const float* fd = feat_dst + ((size_t)r * N + n) * F;
    const float* sn = sum + ((size_t)r * N + n) * F;
    float inv = 1.0f / fmaxf(cnt[(size_t)r * N + n], 1.0f);
    const float* wsp = w_self + (size_t)r * F * D + d;
    const float* wnp = w_neigh + (size_t)r * F * D + d;
    float acc_self = bias[r * D + d];
    float acc_n = 0.0f;
#pragma unroll
    for (int f = 0; f < F; ++f) {
        acc_self += fd[f] * wsp[(size_t)f * D];
        acc_n += sn[f] * wnp[(size_t)f * D];
    }
    out[idx] = acc_self + acc_n * inv;
}

// ======================= launch =======================
extern "C" void kernel_launch(void* const* d_in, const int* in_sizes, int n_in,
                              void* d_out, int out_size, void* d_ws, size_t ws_size,
                              hipStream_t stream) {
    const int* edges_src = (const int*)d_in[0];
    const int* edges_dst = (const int*)d_in[1];
    const float* feat_u_fwd = (const float*)d_in[2];
    const float* feat_i_fwd = (const float*)d_in[3];
    const float* feat_i_rev = (const float*)d_in[4];
    const float* feat_u_rev = (const float*)d_in[5];
    const float* w_self_fwd = (const float*)d_in[6];
    const float* w_neigh_fwd = (const float*)d_in[7];
    const float* b_fwd = (const float*)d_in[8];
    const float* w_self_rev = (const float*)d_in[9];
    const float* w_neigh_rev = (const float*)d_in[10];
    const float* b_rev = (const float*)d_in[11];

    float* out = (float*)d_out;
    float* out_u = out;
    float* out_i = out + (size_t)U * R * D;

    // sorted (2*TE) + S/ghist in-place (GTOT) + psum (2048)  ~= 86.0 MB
    size_t need = ((size_t)2 * TE + (size_t)GTOT + 2048ull) * 4ull;
    if (ws_size >= need) {
        unsigned* sorted = (unsigned*)d_ws;            // 2*TE
        unsigned* S = sorted + (size_t)2 * TE;         // GTOT (scanned in place)
        unsigned* psum = S + GTOT;                     // 2048

        phaseA<<<NBLK, BSZ, 0, stream>>>(edges_src, edges_dst, S);
        scan1<<<NS1, BSZ, 0, stream>>>(S, psum);
        scan2<<<1, BSZ, 0, stream>>>(psum);
        scan3<<<NS1, BSZ, 0, stream>>>(S, psum);
        phaseC<<<NBLK, BSZ, 0, stream>>>(edges_src, edges_dst, S, sorted);
        phaseD<<<NBU_T, BSZ, 0, stream>>>(sorted, S,
                                          feat_i_rev, feat_u_rev, w_self_rev, w_neigh_rev, b_rev,
                                          feat_u_fwd, feat_i_fwd, w_self_fwd, w_neigh_fwd, b_fwd,
                                          out_u, out_i);
    } else {
        // fallback: round-1 global-atomic path
        float* ws = (float*)d_ws;
        hipMemsetAsync(d_ws, 0, WS_FLOATS * sizeof(float), stream);
        scatter_edges<<<4096, 256, 0, stream>>>(edges_src, edges_dst, feat_u_fwd, feat_i_rev, ws);
        finalize_nodes<<<(U * R * D + 255) / 256, 256, 0, stream>>>(
            U, feat_u_rev, w_self_rev, w_neigh_rev, b_rev, ws + SUM_U_OFF, ws + CNT_U_OFF, out_u);
        finalize_nodes<<<(M * R * D + 255) / 256, 256, 0, stream>>>(
            M, feat_i_fwd, w_self_fwd, w_neigh_fwd, b_fwd, ws + SUM_I_OFF, ws + CNT_I_OFF, out_i);
    }
}